// Round 13
// baseline (384.169 us; speedup 1.0000x reference)
//
#include <hip/hip_runtime.h>
#include <cstddef>

#define BB 8
#define SS 1024
#define DD 768
#define HH 8
#define DKK 96
#define FFF 1024
#define MM (BB*SS)
#define QVW 1536                       // merged Q|KV row width
#define SM_SCALE 0.10206207261596577f  // 1/sqrt(96)
#define NT2 8                          // 128-row q-tiles

typedef unsigned short ushort_t;
typedef short short8 __attribute__((ext_vector_type(8)));
typedef float f32x4 __attribute__((ext_vector_type(4)));
typedef float f32x16 __attribute__((ext_vector_type(16)));
typedef ushort_t us4 __attribute__((ext_vector_type(4)));
typedef unsigned uint2v __attribute__((ext_vector_type(2)));

__device__ __forceinline__ ushort_t f2b(float f) {
    union { float f; unsigned u; } x; x.f = f;
    unsigned r = x.u + 0x7fffu + ((x.u >> 16) & 1u);   // RNE
    return (ushort_t)(r >> 16);
}
__device__ __forceinline__ float b2f(ushort_t u) {
    union { unsigned u; float f; } x; x.u = ((unsigned)u) << 16;
    return x.f;
}
// async global->LDS, 16B per lane; LDS dest = wave-uniform base + lane*16
__device__ __forceinline__ void gload16(const ushort_t* g, void* lds_base) {
    __builtin_amdgcn_global_load_lds(
        (const __attribute__((address_space(1))) unsigned int*)g,
        (__attribute__((address_space(3))) unsigned int*)lds_base, 16, 0, 0);
}
// swap vdst.hi32lanes <-> src0.lo32lanes; returns both updated values
__device__ __forceinline__ void plswap(unsigned& a, unsigned& b) {
#if __has_builtin(__builtin_amdgcn_permlane32_swap)
    uint2v r = __builtin_amdgcn_permlane32_swap(a, b, false, false);
    a = r[0]; b = r[1];
#else
    asm("v_permlane32_swap_b32 %0, %1" : "+v"(a), "+v"(b));
#endif
}

// ---------------------------------------------------------------------------
// Fused preprocessing: one 1-D launch covering
//   [0, 2304):    4x DDxDD weight cast+transpose (Wq/Wv of both layers)
//   [2304, 3072): f_W1 (DDxFFF) cast+transpose
//   [3072, 3840): f_W2 (FFFxDD) cast+transpose
//   [3840, 9984): x0 fp32 -> bf16 cast (float4 per thread)
// ---------------------------------------------------------------------------
__device__ __forceinline__ void castWT_body(
    const float* __restrict__ W, ushort_t* __restrict__ Wt,
    int K, int N, int bx, int by)
{
    __shared__ float T[32][33];
    const int tx = threadIdx.x & 31, ty = threadIdx.x >> 5;
    const int n0 = bx * 32, k0 = by * 32;
    #pragma unroll
    for (int r = 0; r < 4; ++r)
        T[ty + 8*r][tx] = W[(size_t)(k0 + ty + 8*r) * N + n0 + tx];
    __syncthreads();
    #pragma unroll
    for (int r = 0; r < 4; ++r)
        Wt[(size_t)(n0 + ty + 8*r) * K + k0 + tx] = f2b(T[tx][ty + 8*r]);
}

__global__ __launch_bounds__(256) void prep_all(
    const float* __restrict__ Wqa, const float* __restrict__ Wva,
    const float* __restrict__ Wqb, const float* __restrict__ Wvb,
    ushort_t* __restrict__ Tqa, ushort_t* __restrict__ Tva,
    ushort_t* __restrict__ Tqb, ushort_t* __restrict__ Tvb,
    const float* __restrict__ W1, ushort_t* __restrict__ T1,
    const float* __restrict__ W2, ushort_t* __restrict__ T2,
    const float* __restrict__ x, ushort_t* __restrict__ xb)
{
    const int id = blockIdx.x;
    if (id < 2304) {
        const int z = id / 576, r = id % 576;
        const float* W = (z == 0) ? Wqa : (z == 1) ? Wva : (z == 2) ? Wqb : Wvb;
        ushort_t* Wt   = (z == 0) ? Tqa : (z == 1) ? Tva : (z == 2) ? Tqb : Tvb;
        castWT_body(W, Wt, DD, DD, r % 24, r / 24);
    } else if (id < 3072) {
        const int r = id - 2304;
        castWT_body(W1, T1, DD, FFF, r % 32, r / 32);
    } else if (id < 3840) {
        const int r = id - 3072;
        castWT_body(W2, T2, FFF, DD, r % 24, r / 24);
    } else {
        const int i = (id - 3840) * 256 + threadIdx.x;
        const float4 v = ((const float4*)x)[i];
        us4 o; o.x = f2b(v.x); o.y = f2b(v.y); o.z = f2b(v.z); o.w = f2b(v.w);
        ((us4*)xb)[i] = o;
    }
}

// ---------------------------------------------------------------------------
// MFMA GEMM: C(bf16) = A(MxK) @ Bt(NxK)^T + bias. 128x128, BK=64, 4 waves.
// DOUBLE-BUFFERED staging (64 KB LDS): prefetch tile k+1 at iter top, one
// barrier per iter. C-tile epilogue aliases the staging buffer. 1-D grid
// with bijective XCD swizzle.
// ---------------------------------------------------------------------------
template<int RELU>
__global__ __launch_bounds__(256) void gemm_bt(
    const ushort_t* __restrict__ A, const ushort_t* __restrict__ Bt,
    const float* __restrict__ bias, const float* __restrict__ bias2, int bN,
    ushort_t* __restrict__ C, int K, int N)
{
    __shared__ ushort_t S[4*128*64];           // As0|As1|Bs0|Bs1 (64 KB); C-tile aliases
    const int tid  = threadIdx.x;
    const int lane = tid & 63, wave = tid >> 6;
    const int wm = wave >> 1, wn = wave & 1;
    const int n = lane & 15, quad = lane >> 4;
    const int sx = n & 7;              // read-side swizzle key
    // XCD-aware bijective remap: contiguous tile chunk per XCD for L2 reuse
    const int nbx = N >> 7;
    const int cpx = gridDim.x >> 3;
    const int sw  = (blockIdx.x & 7) * cpx + (blockIdx.x >> 3);
    const int bm = (sw / nbx) * 128, bn = (sw % nbx) * 128;

    f32x4 acc[4][4];
    #pragma unroll
    for (int i = 0; i < 4; ++i)
        #pragma unroll
        for (int j = 0; j < 4; ++j) acc[i][j] = (f32x4){0.f, 0.f, 0.f, 0.f};

    // stage tile k0 into buffer buf
    auto stage = [&](int k0, int buf) {
        char* abase = (char*)S + buf * 16384;
        char* bbase = (char*)S + 32768 + buf * 16384;
        #pragma unroll
        for (int it = 0; it < 4; ++it) {
            const int u   = (it*4 + wave)*64 + lane;   // LDS 16B unit, 0..1023
            const int row = u >> 3;
            const int c   = (u & 7) ^ (row & 7);       // swizzled global chunk
            gload16(A  + (size_t)(bm + row) * K + k0 + c*8, abase + (it*4 + wave)*1024);
            gload16(Bt + (size_t)(bn + row) * K + k0 + c*8, bbase + (it*4 + wave)*1024);
        }
    };

    stage(0, 0);
    __syncthreads();                 // drains prologue staging
    int cur = 0;
    for (int k0 = 0; k0 < K; k0 += 64) {
        if (k0 + 64 < K) stage(k0 + 64, cur ^ 1);   // prefetch, hidden under MFMA
        const ushort_t* As = S + cur * 8192;
        const ushort_t* Bs = S + 16384 + cur * 8192;
        #pragma unroll
        for (int ks = 0; ks < 2; ++ks) {
            short8 af[4], bf[4];
            #pragma unroll
            for (int i = 0; i < 4; ++i)
                af[i] = *(short8*)&As[((wm*64 + i*16 + n)*8 + ((ks*4 + quad) ^ sx))*8];
            #pragma unroll
            for (int j = 0; j < 4; ++j)
                bf[j] = *(short8*)&Bs[((wn*64 + j*16 + n)*8 + ((ks*4 + quad) ^ sx))*8];
            __builtin_amdgcn_s_setprio(1);
            #pragma unroll
            for (int i = 0; i < 4; ++i)
                #pragma unroll
                for (int j = 0; j < 4; ++j)
                    acc[i][j] = __builtin_amdgcn_mfma_f32_16x16x32_bf16(af[i], bf[j], acc[i][j], 0, 0, 0);
            __builtin_amdgcn_s_setprio(0);
        }
        __syncthreads();             // reads of cur done; prefetch into cur^1 drained
        cur ^= 1;
    }
    // epilogue: acc -> LDS C-tile (bf16, padded rows, aliases S) -> b128 stores
    #pragma unroll
    for (int j = 0; j < 4; ++j) {
        const int col = wn*64 + j*16 + n;
        const int gcol = bn + col;
        const float bsv = (gcol < bN) ? bias[gcol] : bias2[gcol - bN];
        #pragma unroll
        for (int i = 0; i < 4; ++i) {
            const int lrow = wm*64 + i*16 + quad*4;
            #pragma unroll
            for (int r = 0; r < 4; ++r) {
                float v = acc[i][j][r] + bsv;
                if (RELU) v = fmaxf(v, 0.f);
                S[(lrow + r)*136 + col] = f2b(v);
            }
        }
    }
    __syncthreads();
    #pragma unroll
    for (int it = 0; it < 8; ++it) {
        const int u = it*256 + tid;              // 0..2047 b128 units
        const int grow = u >> 4, gc = u & 15;
        *(short8*)(C + (size_t)(bm + grow)*N + bn + gc*8) = *(short8*)&S[grow*136 + gc*8];
    }
}

// ---------------------------------------------------------------------------
// Pass 1: column sums. 128-row q-tile, 8 waves, double-buffered K staging,
// XCD-grouped 1D grid (256 blocks). lpart[b,h,qt2(8),k] partial column sums.
// ---------------------------------------------------------------------------
__global__ __launch_bounds__(512) void attn_sums(
    const ushort_t* __restrict__ QV, const int* __restrict__ amask,
    float* __restrict__ lpart)
{
    __shared__ ushort_t Qs[128*128];     // 32 KB (128 rows x 256B, swizzled)
    __shared__ ushort_t Ks[2][64*128];   // 2 x 16 KB
    __shared__ float colsum[2][8][64];   // double-buffered per-wave partials
    const int tid = threadIdx.x, lane = tid & 63, wave = tid >> 6;
    const int n = lane & 15, quad = lane >> 4, sx = n & 7;
    const int hwid = blockIdx.x;
    const int v = (hwid & 7) * 32 + (hwid >> 3);   // XCD-group same (b,h)
    const int px = v & 3, h = (v >> 2) & 7, b = v >> 5;
    const ushort_t* Qh = QV + (size_t)b*SS*QVW + h*DKK;
    const ushort_t* Kh = QV + (size_t)b*SS*QVW + DD + h*DKK;
    float* lpq = lpart + (size_t)(b*HH + h)*NT2*SS;

    #pragma unroll
    for (int half = 0; half < 2; ++half) {
        const int qt2 = half ? (7 - px) : px;
        const int q0 = qt2 * 128;
        const int ktmax = 2*qt2 + 1;
        // stage Q tile (128 rows x 12 chunks, swizzled into 256B rows)
        #pragma unroll
        for (int it = 0; it < 4; ++it) {
            const int u = (it*8 + wave)*64 + lane;
            const int row = u >> 4, c = (u & 15) ^ (row & 7);
            if (c < 12)
                gload16(Qh + (size_t)(q0 + row)*QVW + c*8, (char*)Qs + (it*8 + wave)*1024);
        }
        const int4 mv = *(const int4*)&amask[b*SS + q0 + wave*16 + quad*4];
        const int mr[4] = {mv.x, mv.y, mv.z, mv.w};
        // stage K tile kt=0 into buf 0
        #pragma unroll
        for (int it = 0; it < 2; ++it) {
            const int u = (it*8 + wave)*64 + lane;
            const int row = u >> 4, c = (u & 15) ^ (row & 7);
            if (c < 12)
                gload16(Kh + (size_t)row*QVW + c*8, (char*)Ks[0] + (it*8 + wave)*1024);
        }
        __syncthreads();
        // hoist Q fragments (loop-invariant across kt)
        short8 aq[3];
        #pragma unroll
        for (int ks = 0; ks < 3; ++ks)
            aq[ks] = *(short8*)&Qs[((wave*16 + n)*16 + ((ks*4 + quad) ^ sx))*8];

        int cur = 0;
        for (int kt = 0; kt <= ktmax; ++kt) {
            const int k0 = kt * 64;
            if (kt < ktmax) {   // prefetch next K tile
                #pragma unroll
                for (int it = 0; it < 2; ++it) {
                    const int u = (it*8 + wave)*64 + lane;
                    const int row = u >> 4, c = (u & 15) ^ (row & 7);
                    if (c < 12)
                        gload16(Kh + (size_t)(k0 + 64 + row)*QVW + c*8,
                                (char*)Ks[cur^1] + (it*8 + wave)*1024);
                }
            }
            // flush previous iteration's colsum (wave 0 only)
            if (kt > 0 && tid < 64) {
                const float s = colsum[cur^1][0][tid] + colsum[cur^1][1][tid]
                              + colsum[cur^1][2][tid] + colsum[cur^1][3][tid]
                              + colsum[cur^1][4][tid] + colsum[cur^1][5][tid]
                              + colsum[cur^1][6][tid] + colsum[cur^1][7][tid];
                lpq[(size_t)qt2*SS + (k0 - 64) + tid] = s;
            }
            #pragma unroll
            for (int ns = 0; ns < 4; ++ns) {
                f32x4 sa = (f32x4){0.f, 0.f, 0.f, 0.f};
                __builtin_amdgcn_s_setprio(1);
                #pragma unroll
                for (int ks = 0; ks < 3; ++ks) {
                    const short8 bk = *(short8*)&Ks[cur][((ns*16 + n)*16 + ((ks*4 + quad) ^ sx))*8];
                    sa = __builtin_amdgcn_mfma_f32_16x16x32_bf16(aq[ks], bk, sa, 0, 0, 0);
                }
                __builtin_amdgcn_s_setprio(0);
                const int kl = ns*16 + n;
                const int keyg = k0 + kl;
                float s = 0.f;
                #pragma unroll
                for (int r = 0; r < 4; ++r) {
                    const int qg = q0 + wave*16 + quad*4 + r;
                    const bool dead = (mr[r] != 0) || (keyg > qg);
                    s += dead ? 0.f : __expf(sa[r] * SM_SCALE);
                }
                s += __shfl_xor(s, 16);
                s += __shfl_xor(s, 32);
                if (quad == 0) colsum[cur][wave][kl] = s;
            }
            __syncthreads();
            cur ^= 1;
        }
        // final flush: last iter wrote colsum[ktmax&1] (= 1, ktmax odd)
        if (tid < 64) {
            const int pb = ktmax & 1;
            const float s = colsum[pb][0][tid] + colsum[pb][1][tid]
                          + colsum[pb][2][tid] + colsum[pb][3][tid]
                          + colsum[pb][4][tid] + colsum[pb][5][tid]
                          + colsum[pb][6][tid] + colsum[pb][7][tid];
            lpq[(size_t)qt2*SS + ktmax*64 + tid] = s;
        }
    }
}

// ---------------------------------------------------------------------------
// V' transpose+scale: QV's KV half -> (B,H,DK,S) bf16 scaled by 1/l_k, where
// l_k = sum over qt2 (128-row tiles) >= k0>>7 of lpart. grid (S/64, H, B).
// ---------------------------------------------------------------------------
__global__ __launch_bounds__(256) void transpose_scale(
    const ushort_t* __restrict__ QV, const float* __restrict__ lpart,
    ushort_t* __restrict__ Vt)
{
    __shared__ ushort_t T[64][104];
    __shared__ float rlv[64];
    const int tid = threadIdx.x;
    const int k0 = blockIdx.x * 64, h = blockIdx.y, b = blockIdx.z;
    const ushort_t* src = QV + (size_t)b*SS*QVW + DD + h*DKK;
    for (int s = tid; s < 768; s += 256) {
        const int r = s / 12, c = s % 12;
        *(short8*)&T[r][c*8] = *(const short8*)(src + (size_t)(k0 + r)*QVW + c*8);
    }
    if (tid < 64) {
        const float* lp = lpart + (size_t)(b*HH + h)*NT2*SS;
        float l = 0.f;
        for (int qt2 = k0 >> 7; qt2 < NT2; ++qt2) l += lp[(size_t)qt2*SS + k0 + tid];
        rlv[tid] = (l > 0.f) ? (1.f / l) : 0.f;
    }
    __syncthreads();
    ushort_t* dst = Vt + ((size_t)b*HH + h)*DKK*SS;
    for (int s = tid; s < 768; s += 256) {
        const int dk = s >> 3, c = s & 7;
        short8 v;
        #pragma unroll
        for (int i = 0; i < 8; ++i)
            v[i] = (short)f2b(b2f(T[c*8 + i][dk]) * rlv[c*8 + i]);
        *(short8*)(dst + (size_t)dk*SS + k0 + c*8) = v;
    }
}

// ---------------------------------------------------------------------------
// Pass 2: fused recompute + PV, 32x32 MFMA with swapped QK^T. 4 waves x
// 32 q-rows = 128-row tile. K/V double-buffered in LDS (gload16); E never
// touches LDS; cvt_pk_bf16 + permlane32_swap rearrange E into the PV
// A-fragment. Epilogue stages C-tile in LDS (aliases Ks) for coalesced b128
// O stores. Vt pre-scaled; XCD-grouped 1D grid (256 blocks).
// ---------------------------------------------------------------------------
__global__ __launch_bounds__(256, 2) void attn_pv_re(
    const ushort_t* __restrict__ QV, const int* __restrict__ amask,
    const ushort_t* __restrict__ Vt, ushort_t* __restrict__ O)
{
    __shared__ ushort_t Ks[2][64*128]; // 2 x 16 KB; epilogue C-tile aliases
    __shared__ ushort_t Vs[2][96*64];  // 2 x 12 KB, 96 d-rows x 8 chunks (swz)
    const int tid = threadIdx.x, lane = tid & 63, wave = tid >> 6;
    const int ln31 = lane & 31, hi = lane >> 5;
    const int hwid = blockIdx.x;
    const int v = (hwid & 7) * 32 + (hwid >> 3);   // XCD-group same (b,h)
    const int px = v & 3, h = (v >> 2) & 7, b = v >> 5;
    const ushort_t* Qh = QV + (size_t)b*SS*QVW + h*DKK;
    const ushort_t* Kh = QV + (size_t)b*SS*QVW + DD + h*DKK;
    const ushort_t* Vth = Vt + ((size_t)b*HH + h)*DKK*SS;

    #pragma unroll
    for (int half = 0; half < 2; ++half) {
        const int qt2 = half ? (7 - px) : px;
        const int q0 = qt2 * 128;
        const int ktmax = 2*qt2 + 1;
        const int qrow = q0 + wave*32 + ln31;
        // Q B-fragments (loop-invariant): Q[qrow][dk = t*16 + hi*8 .. +8]
        short8 bq[6];
        #pragma unroll
        for (int t = 0; t < 6; ++t)
            bq[t] = *(const short8*)(Qh + (size_t)qrow*QVW + t*16 + hi*8);
        const bool padq = amask[b*SS + qrow] != 0;

        // stage kt=0 into buf 0
        #pragma unroll
        for (int it = 0; it < 4; ++it) {
            const int u = (it*4 + wave)*64 + lane;     // 0..1023
            const int row = u >> 4, c = (u & 15) ^ (row & 7);
            if (c < 12)
                gload16(Kh + (size_t)row*QVW + c*8, (char*)Ks[0] + (it*4 + wave)*1024);
        }
        #pragma unroll
        for (int it = 0; it < 3; ++it) {
            const int u = (it*4 + wave)*64 + lane;     // 0..767
            const int row = u >> 3, c = (u & 7) ^ (row & 7);
            gload16(Vth + (size_t)row*SS + c*8, (char*)Vs[0] + (it*4 + wave)*1024);
        }
        __syncthreads();

        f32x16 acc[3];
        #pragma unroll
        for (int db = 0; db < 3; ++db)
            #pragma unroll
            for (int i = 0; i < 16; ++i) acc[db][i] = 0.f;

        int cur = 0;
        for (int kt = 0; kt <= ktmax; ++kt) {
            const int k0 = kt * 64;
            if (kt < ktmax) {   // prefetch next K/V tiles (hide under full iter)
                #pragma unroll
                for (int it = 0; it < 4; ++it) {
                    const int u = (it*4 + wave)*64 + lane;
                    const int row = u >> 4, c = (u & 15) ^ (row & 7);
                    if (c < 12)
                        gload16(Kh + (size_t)(k0 + 64 + row)*QVW + c*8,
                                (char*)Ks[cur^1] + (it*4 + wave)*1024);
                }
                #pragma unroll
                for (int it = 0; it < 3; ++it) {
                    const int u = (it*4 + wave)*64 + lane;
                    const int row = u >> 3, c = (u & 7) ^ (row & 7);
                    gload16(Vth + (size_t)row*SS + k0 + 64 + c*8,
                            (char*)Vs[cur^1] + (it*4 + wave)*1024);
                }
            }
            #pragma unroll
            for (int kb = 0; kb < 2; ++kb) {
                // swapped QK^T: D[k][q], q = ln31
                f32x16 sk;
                #pragma unroll
                for (int i = 0; i < 16; ++i) sk[i] = 0.f;
                const int krow = kb*32 + ln31;
                __builtin_amdgcn_s_setprio(1);
                #pragma unroll
                for (int t = 0; t < 6; ++t) {
                    const short8 ak = *(short8*)&Ks[cur][krow*128 + (((t*2 + hi) ^ (krow & 7))*8)];
                    sk = __builtin_amdgcn_mfma_f32_32x32x16_bf16(ak, bq[t], sk, 0, 0, 0);
                }
                __builtin_amdgcn_s_setprio(0);
                // mask + exp (register-local: lane owns q-row qrow)
                const int kbase = k0 + kb*32 + 4*hi;
                float p[16];
                #pragma unroll
                for (int r = 0; r < 16; ++r) {
                    const int kg = kbase + (r & 3) + 8*(r >> 2);
                    const bool dead = padq || (kg > qrow);
                    p[r] = dead ? 0.f : __expf(sk[r] * SM_SCALE);
                }
                // pack f32->bf16 pairs, then swap halves across lane<32/>=32
                unsigned w[8];
                #pragma unroll
                for (int i = 0; i < 8; ++i)
                    asm("v_cvt_pk_bf16_f32 %0, %1, %2" : "=v"(w[i]) : "v"(p[2*i]), "v"(p[2*i+1]));
                plswap(w[0], w[2]);
                plswap(w[1], w[3]);
                plswap(w[4], w[6]);
                plswap(w[5], w[7]);
                // PV: acc[q][d] += E[q][k] * V'[dk][k]
                __builtin_amdgcn_s_setprio(1);
                #pragma unroll
                for (int s = 0; s < 2; ++s) {
                    short8 ae;
                    unsigned* aeu = (unsigned*)&ae;
                    aeu[0] = w[s*4 + 0]; aeu[1] = w[s*4 + 1];
                    aeu[2] = w[s*4 + 2]; aeu[3] = w[s*4 + 3];
                    #pragma unroll
                    for (int db = 0; db < 3; ++db) {
                        const int drow = db*32 + ln31;
                        const short8 bv = *(short8*)&Vs[cur][drow*64 + (((kb*4 + s*2 + hi) ^ (drow & 7))*8)];
                        acc[db] = __builtin_amdgcn_mfma_f32_32x32x16_bf16(ae, bv, acc[db], 0, 0, 0);
                    }
                }
                __builtin_amdgcn_s_setprio(0);
            }
            __syncthreads();
            cur ^= 1;
        }
        // epilogue: acc -> LDS C-tile 128x104 (aliases Ks) -> b128 O stores
        {
            ushort_t* Ct = (ushort_t*)Ks;
            #pragma unroll
            for (int db = 0; db < 3; ++db) {
                #pragma unroll
                for (int r = 0; r < 16; ++r) {
                    const int lq = wave*32 + (r & 3) + 8*(r >> 2) + 4*hi;
                    Ct[lq*104 + db*32 + ln31] = f2b(acc[db][r]);
                }
            }
            __syncthreads();
            ushort_t* Oq = O + ((size_t)b*SS + q0)*DD + h*DKK;
            #pragma unroll
            for (int it = 0; it < 6; ++it) {
                const int u = it*256 + tid;          // 0..1535 b128 units
                const int row = u / 12, c = u % 12;
                *(short8*)(Oq + (size_t)row*DD + c*8) = *(short8*)&Ct[row*104 + c*8];
            }
            __syncthreads();   // before next half's staging overwrites Ks
        }
    }
}

// ---------------------------------------------------------------------------
// Residual + LayerNorm, vectorized (4 elems/thread, threads 0..191 active).
// X, R dtype per template; writes bf16 (or fp32 final). One block per row.
// ---------------------------------------------------------------------------
__device__ __forceinline__ float block_sum256(float s, float* tmp4)
{
    #pragma unroll
    for (int off = 32; off > 0; off >>= 1) s += __shfl_down(s, off);
    __syncthreads();
    if ((threadIdx.x & 63) == 0) tmp4[threadIdx.x >> 6] = s;
    __syncthreads();
    return tmp4[0] + tmp4[1] + tmp4[2] + tmp4[3];
}

template<int XBF, int RBF, int OUTF32>
__global__ __launch_bounds__(256) void resid_ln(
    const void* __restrict__ X, const void* __restrict__ R,
    const float* __restrict__ g, const float* __restrict__ beta,
    ushort_t* __restrict__ OutB, float* __restrict__ OutF)
{
    __shared__ float tmp4[4];
    const int row = blockIdx.x;
    const int tid = threadIdx.x;
    const int c4 = tid * 4;
    const bool act = tid < 192;            // 192*4 = 768 elements
    float v[4] = {0.f, 0.f, 0.f, 0.f};
    float s = 0.f;
    if (act) {
        const size_t base = (size_t)row * DD + c4;
        float xv[4], rv[4];
        if (XBF) {
            const us4 x4 = *(const us4*)&((const ushort_t*)X)[base];
            xv[0] = b2f(x4.x); xv[1] = b2f(x4.y); xv[2] = b2f(x4.z); xv[3] = b2f(x4.w);
        } else {
            const float4 x4 = *(const float4*)&((const float*)X)[base];
            xv[0] = x4.x; xv[1] = x4.y; xv[2] = x4.z; xv[3] = x4.w;
        }
        if (RBF) {
            const us4 r4 = *(const us4*)&((const ushort_t*)R)[base];
            rv[0] = b2f(r4.x); rv[1] = b2f(r4.y); rv[2] = b2f(r4.z); rv[3] = b2f(r4.w);
        } else {
            const float4 r4 = *(const float4*)&((const float*)R)[base];
            rv[0] = r4.x; rv[1] = r4.y; rv[2] = r4.z; rv[3] = r4.w;
        }
        #pragma unroll
        for (int i = 0; i < 4; ++i) { v[i] = xv[i] + rv[i]; s += v[i]; }
    }
    const float mu = block_sum256(s, tmp4) * (1.f / DD);
    float qv = 0.f;
    if (act) {
        #pragma unroll
        for (int i = 0; i < 4; ++i) { const float d = v[i] - mu; qv += d * d; }
    }
    const float inv = rsqrtf(block_sum256(qv, tmp4) * (1.f / DD) + 1e-5f);
    if (act) {
        const float4 gv = *(const float4*)&g[c4];
        const float4 bv = *(const float4*)&beta[c4];
        float o[4];
        o[0] = (v[0] - mu) * inv * gv.x + bv.x;
        o[1] = (v[1] - mu) * inv * gv.y + bv.y;
        o[2] = (v[2] - mu) * inv * gv.z + bv.z;
        o[3] = (v[3] - mu) * inv * gv.w + bv.w;
        if (OUTF32) {
            float4 of = {o[0], o[1], o[2], o[3]};
            *(float4*)&OutF[(size_t)row * DD + c4] = of;
        } else {
            us4 ob;
            ob.x = f2b(o[0]); ob.y = f2b(o[1]); ob.z = f2b(o[2]); ob.w = f2b(o[3]);
            *(us4*)&OutB[(size_t)row * DD + c4] = ob;
        }
    }
}

// ---------------------------------------------------------------------------
extern "C" void kernel_launch(void* const* d_in, const int* in_sizes, int n_in,
                              void* d_out, int out_size, void* d_ws, size_t ws_size,
                              hipStream_t stream)
{
    (void)in_sizes; (void)n_in; (void)out_size; (void)ws_size;
    const float* x0    = (const float*)d_in[0];
    const int*   amask = (const int*)d_in[1];
    const float* a1_Wq = (const float*)d_in[2];
    const float* a1_bq = (const float*)d_in[3];
    const float* a1_Wv = (const float*)d_in[4];
    const float* a1_bv = (const float*)d_in[5];
    const float* a1_g  = (const float*)d_in[6];
    const float* a1_b  = (const float*)d_in[7];
    const float* a2_Wq = (const float*)d_in[8];
    const float* a2_bq = (const float*)d_in[9];
    const float* a2_Wv = (const float*)d_in[10];
    const float* a2_bv = (const float*)d_in[11];
    const float* a2_g  = (const float*)d_in[12];
    const float* a2_b  = (const float*)d_in[13];
    const float* f_W1  = (const float*)d_in[14];
    const float* f_b1  = (const float*)d_in[15];
    const float* f_W2  = (const float*)d_in[16];
    const float* f_b2  = (const float*)d_in[17];
    const float* f_g   = (const float*)d_in[18];
    const float* f_b   = (const float*)d_in[19];

    char* ws = (char*)d_ws;
    size_t off = 0;
    auto alloc = [&](size_t bytes) { void* p = ws + off; off += (bytes + 255) & ~(size_t)255; return p; };
    ushort_t* WqvT1 = (ushort_t*)alloc((size_t)QVW*DD*2);   // rows 0..767 Wq^T, 768..1535 Wv^T
    ushort_t* WqvT2 = (ushort_t*)alloc((size_t)QVW*DD*2);
    ushort_t* W1T   = (ushort_t*)alloc((size_t)DD*FFF*2);
    ushort_t* W2T   = (ushort_t*)alloc((size_t)DD*FFF*2);
    ushort_t* xb0   = (ushort_t*)alloc((size_t)MM*DD*2);    // bf16(x0)
    ushort_t* xb1   = (ushort_t*)alloc((size_t)MM*DD*2);    // x1 (post-LN layer 1)
    ushort_t* xb2   = (ushort_t*)alloc((size_t)MM*DD*2);    // x2 (post-LN layer 2)
    ushort_t* Ob    = (ushort_t*)alloc((size_t)MM*DD*2);    // attention O / FFN y
    ushort_t* QVb   = (ushort_t*)alloc((size_t)MM*QVW*2);   // Q | KV merged; aliased as hb
    ushort_t* hb    = QVb;                                  // M x FF bf16
    ushort_t* Vtb   = (ushort_t*)alloc((size_t)MM*DD*2);    // (B,H,DK,S) scaled V^T
    float* lpart = (float*)alloc((size_t)BB*HH*NT2*SS*4);   // 2 MB partial column sums
    float* out = (float*)d_out;

    const dim3 blk(256);
    const dim3 blk512(512);
    const dim3 gat(256);               // XCD-swizzled 1D grid for both attn passes
    const dim3 gtr(SS/64, HH, BB);

    prep_all<<<dim3(9984), blk, 0, stream>>>(
        a1_Wq, a1_Wv, a2_Wq, a2_Wv,
        WqvT1, WqvT1 + (size_t)DD*DD, WqvT2, WqvT2 + (size_t)DD*DD,
        f_W1, W1T, f_W2, W2T, x0, xb0);

    // ---- layer 1 ----
    gemm_bt<0><<<dim3((QVW/128)*(MM/128)), blk, 0, stream>>>(xb0, WqvT1, a1_bq, a1_bv, DD, QVb, DD, QVW);
    attn_sums<<<gat, blk512, 0, stream>>>(QVb, amask, lpart);
    transpose_scale<<<gtr, blk, 0, stream>>>(QVb, lpart, Vtb);
    attn_pv_re<<<gat, blk, 0, stream>>>(QVb, amask, Vtb, Ob);
    resid_ln<1,0,0><<<dim3(MM), blk, 0, stream>>>(Ob, x0, a1_g, a1_b, xb1, nullptr);

    // ---- layer 2 ----
    gemm_bt<0><<<dim3((QVW/128)*(MM/128)), blk, 0, stream>>>(xb1, WqvT2, a2_bq, a2_bv, DD, QVb, DD, QVW);
    attn_sums<<<gat, blk512, 0, stream>>>(QVb, amask, lpart);
    transpose_scale<<<gtr, blk, 0, stream>>>(QVb, lpart, Vtb);
    attn_pv_re<<<gat, blk, 0, stream>>>(QVb, amask, Vtb, Ob);
    resid_ln<1,1,0><<<dim3(MM), blk, 0, stream>>>(Ob, xb1, a2_g, a2_b, xb2, nullptr);

    // ---- FFN ----
    gemm_bt<1><<<dim3((FFF/128)*(MM/128)), blk, 0, stream>>>(xb2, W1T, f_b1, f_b1, FFF, hb, DD, FFF);
    gemm_bt<0><<<dim3((DD/128)*(MM/128)), blk, 0, stream>>>(hb, W2T, f_b2, f_b2, DD, Ob, FFF, DD);
    resid_ln<1,1,1><<<dim3(MM), blk, 0, stream>>>(Ob, xb2, f_g, f_b, nullptr, out);
}

// Round 14
// 372.364 us; speedup vs baseline: 1.0317x; 1.0317x over previous
//
#include <hip/hip_runtime.h>
#include <cstddef>

#define BB 8
#define SS 1024
#define DD 768
#define HH 8
#define DKK 96
#define FFF 1024
#define MM (BB*SS)
#define QVW 1536                       // merged Q|KV row width
#define SM_SCALE 0.10206207261596577f  // 1/sqrt(96)
#define NT2 8                          // 128-row q-tiles

typedef unsigned short ushort_t;
typedef short short8 __attribute__((ext_vector_type(8)));
typedef float f32x4 __attribute__((ext_vector_type(4)));
typedef float f32x16 __attribute__((ext_vector_type(16)));
typedef ushort_t us4 __attribute__((ext_vector_type(4)));
typedef unsigned uint2v __attribute__((ext_vector_type(2)));

__device__ __forceinline__ ushort_t f2b(float f) {
    union { float f; unsigned u; } x; x.f = f;
    unsigned r = x.u + 0x7fffu + ((x.u >> 16) & 1u);   // RNE
    return (ushort_t)(r >> 16);
}
__device__ __forceinline__ float b2f(ushort_t u) {
    union { unsigned u; float f; } x; x.u = ((unsigned)u) << 16;
    return x.f;
}
// async global->LDS, 16B per lane; LDS dest = wave-uniform base + lane*16
__device__ __forceinline__ void gload16(const ushort_t* g, void* lds_base) {
    __builtin_amdgcn_global_load_lds(
        (const __attribute__((address_space(1))) unsigned int*)g,
        (__attribute__((address_space(3))) unsigned int*)lds_base, 16, 0, 0);
}
// swap vdst.hi32lanes <-> src0.lo32lanes; returns both updated values
__device__ __forceinline__ void plswap(unsigned& a, unsigned& b) {
#if __has_builtin(__builtin_amdgcn_permlane32_swap)
    uint2v r = __builtin_amdgcn_permlane32_swap(a, b, false, false);
    a = r[0]; b = r[1];
#else
    asm("v_permlane32_swap_b32 %0, %1" : "+v"(a), "+v"(b));
#endif
}

// ---------------------------------------------------------------------------
// Fused preprocessing: one 1-D launch covering
//   [0, 2304):    4x DDxDD weight cast+transpose (Wq/Wv of both layers)
//   [2304, 3072): f_W1 (DDxFFF) cast+transpose
//   [3072, 3840): f_W2 (FFFxDD) cast+transpose
//   [3840, 9984): x0 fp32 -> bf16 cast (float4 per thread)
// ---------------------------------------------------------------------------
__device__ __forceinline__ void castWT_body(
    const float* __restrict__ W, ushort_t* __restrict__ Wt,
    int K, int N, int bx, int by)
{
    __shared__ float T[32][33];
    const int tx = threadIdx.x & 31, ty = threadIdx.x >> 5;
    const int n0 = bx * 32, k0 = by * 32;
    #pragma unroll
    for (int r = 0; r < 4; ++r)
        T[ty + 8*r][tx] = W[(size_t)(k0 + ty + 8*r) * N + n0 + tx];
    __syncthreads();
    #pragma unroll
    for (int r = 0; r < 4; ++r)
        Wt[(size_t)(n0 + ty + 8*r) * K + k0 + tx] = f2b(T[tx][ty + 8*r]);
}

__global__ __launch_bounds__(256) void prep_all(
    const float* __restrict__ Wqa, const float* __restrict__ Wva,
    const float* __restrict__ Wqb, const float* __restrict__ Wvb,
    ushort_t* __restrict__ Tqa, ushort_t* __restrict__ Tva,
    ushort_t* __restrict__ Tqb, ushort_t* __restrict__ Tvb,
    const float* __restrict__ W1, ushort_t* __restrict__ T1,
    const float* __restrict__ W2, ushort_t* __restrict__ T2,
    const float* __restrict__ x, ushort_t* __restrict__ xb)
{
    const int id = blockIdx.x;
    if (id < 2304) {
        const int z = id / 576, r = id % 576;
        const float* W = (z == 0) ? Wqa : (z == 1) ? Wva : (z == 2) ? Wqb : Wvb;
        ushort_t* Wt   = (z == 0) ? Tqa : (z == 1) ? Tva : (z == 2) ? Tqb : Tvb;
        castWT_body(W, Wt, DD, DD, r % 24, r / 24);
    } else if (id < 3072) {
        const int r = id - 2304;
        castWT_body(W1, T1, DD, FFF, r % 32, r / 32);
    } else if (id < 3840) {
        const int r = id - 3072;
        castWT_body(W2, T2, FFF, DD, r % 24, r / 24);
    } else {
        const int i = (id - 3840) * 256 + threadIdx.x;
        const float4 v = ((const float4*)x)[i];
        us4 o; o.x = f2b(v.x); o.y = f2b(v.y); o.z = f2b(v.z); o.w = f2b(v.w);
        ((us4*)xb)[i] = o;
    }
}

// ---------------------------------------------------------------------------
// MFMA GEMM: C(bf16) = A(MxK) @ Bt(NxK)^T + bias. 128x128, BK=64, 4 waves.
// DOUBLE-BUFFERED staging (64 KB LDS): prefetch tile k+1 at iter top, one
// barrier per iter. C-tile epilogue aliases the staging buffer. 1-D grid
// with bijective XCD swizzle.
// ---------------------------------------------------------------------------
template<int RELU>
__global__ __launch_bounds__(256) void gemm_bt(
    const ushort_t* __restrict__ A, const ushort_t* __restrict__ Bt,
    const float* __restrict__ bias, const float* __restrict__ bias2, int bN,
    ushort_t* __restrict__ C, int K, int N)
{
    __shared__ ushort_t S[4*128*64];           // As0|As1|Bs0|Bs1 (64 KB); C-tile aliases
    const int tid  = threadIdx.x;
    const int lane = tid & 63, wave = tid >> 6;
    const int wm = wave >> 1, wn = wave & 1;
    const int n = lane & 15, quad = lane >> 4;
    const int sx = n & 7;              // read-side swizzle key
    // XCD-aware bijective remap: contiguous tile chunk per XCD for L2 reuse
    const int nbx = N >> 7;
    const int cpx = gridDim.x >> 3;
    const int sw  = (blockIdx.x & 7) * cpx + (blockIdx.x >> 3);
    const int bm = (sw / nbx) * 128, bn = (sw % nbx) * 128;

    f32x4 acc[4][4];
    #pragma unroll
    for (int i = 0; i < 4; ++i)
        #pragma unroll
        for (int j = 0; j < 4; ++j) acc[i][j] = (f32x4){0.f, 0.f, 0.f, 0.f};

    // stage tile k0 into buffer buf
    auto stage = [&](int k0, int buf) {
        char* abase = (char*)S + buf * 16384;
        char* bbase = (char*)S + 32768 + buf * 16384;
        #pragma unroll
        for (int it = 0; it < 4; ++it) {
            const int u   = (it*4 + wave)*64 + lane;   // LDS 16B unit, 0..1023
            const int row = u >> 3;
            const int c   = (u & 7) ^ (row & 7);       // swizzled global chunk
            gload16(A  + (size_t)(bm + row) * K + k0 + c*8, abase + (it*4 + wave)*1024);
            gload16(Bt + (size_t)(bn + row) * K + k0 + c*8, bbase + (it*4 + wave)*1024);
        }
    };

    stage(0, 0);
    __syncthreads();                 // drains prologue staging
    int cur = 0;
    for (int k0 = 0; k0 < K; k0 += 64) {
        if (k0 + 64 < K) stage(k0 + 64, cur ^ 1);   // prefetch, hidden under MFMA
        const ushort_t* As = S + cur * 8192;
        const ushort_t* Bs = S + 16384 + cur * 8192;
        #pragma unroll
        for (int ks = 0; ks < 2; ++ks) {
            short8 af[4], bf[4];
            #pragma unroll
            for (int i = 0; i < 4; ++i)
                af[i] = *(short8*)&As[((wm*64 + i*16 + n)*8 + ((ks*4 + quad) ^ sx))*8];
            #pragma unroll
            for (int j = 0; j < 4; ++j)
                bf[j] = *(short8*)&Bs[((wn*64 + j*16 + n)*8 + ((ks*4 + quad) ^ sx))*8];
            __builtin_amdgcn_s_setprio(1);
            #pragma unroll
            for (int i = 0; i < 4; ++i)
                #pragma unroll
                for (int j = 0; j < 4; ++j)
                    acc[i][j] = __builtin_amdgcn_mfma_f32_16x16x32_bf16(af[i], bf[j], acc[i][j], 0, 0, 0);
            __builtin_amdgcn_s_setprio(0);
        }
        __syncthreads();             // reads of cur done; prefetch into cur^1 drained
        cur ^= 1;
    }
    // epilogue: acc -> LDS C-tile (bf16, padded rows, aliases S) -> b128 stores
    #pragma unroll
    for (int j = 0; j < 4; ++j) {
        const int col = wn*64 + j*16 + n;
        const int gcol = bn + col;
        const float bsv = (gcol < bN) ? bias[gcol] : bias2[gcol - bN];
        #pragma unroll
        for (int i = 0; i < 4; ++i) {
            const int lrow = wm*64 + i*16 + quad*4;
            #pragma unroll
            for (int r = 0; r < 4; ++r) {
                float v = acc[i][j][r] + bsv;
                if (RELU) v = fmaxf(v, 0.f);
                S[(lrow + r)*136 + col] = f2b(v);
            }
        }
    }
    __syncthreads();
    #pragma unroll
    for (int it = 0; it < 8; ++it) {
        const int u = it*256 + tid;              // 0..2047 b128 units
        const int grow = u >> 4, gc = u & 15;
        *(short8*)(C + (size_t)(bm + grow)*N + bn + gc*8) = *(short8*)&S[grow*136 + gc*8];
    }
}

// ---------------------------------------------------------------------------
// Pass 1: column sums. 128-row q-tile, 8 waves, double-buffered K staging,
// XCD-grouped 1D grid (256 blocks). lpart[b,h,qt2(8),k] partial column sums.
// ---------------------------------------------------------------------------
__global__ __launch_bounds__(512) void attn_sums(
    const ushort_t* __restrict__ QV, const int* __restrict__ amask,
    float* __restrict__ lpart)
{
    __shared__ ushort_t Qs[128*128];     // 32 KB (128 rows x 256B, swizzled)
    __shared__ ushort_t Ks[2][64*128];   // 2 x 16 KB
    __shared__ float colsum[2][8][64];   // double-buffered per-wave partials
    const int tid = threadIdx.x, lane = tid & 63, wave = tid >> 6;
    const int n = lane & 15, quad = lane >> 4, sx = n & 7;
    const int hwid = blockIdx.x;
    const int v = (hwid & 7) * 32 + (hwid >> 3);   // XCD-group same (b,h)
    const int px = v & 3, h = (v >> 2) & 7, b = v >> 5;
    const ushort_t* Qh = QV + (size_t)b*SS*QVW + h*DKK;
    const ushort_t* Kh = QV + (size_t)b*SS*QVW + DD + h*DKK;
    float* lpq = lpart + (size_t)(b*HH + h)*NT2*SS;

    #pragma unroll
    for (int half = 0; half < 2; ++half) {
        const int qt2 = half ? (7 - px) : px;
        const int q0 = qt2 * 128;
        const int ktmax = 2*qt2 + 1;
        // stage Q tile (128 rows x 12 chunks, swizzled into 256B rows)
        #pragma unroll
        for (int it = 0; it < 4; ++it) {
            const int u = (it*8 + wave)*64 + lane;
            const int row = u >> 4, c = (u & 15) ^ (row & 7);
            if (c < 12)
                gload16(Qh + (size_t)(q0 + row)*QVW + c*8, (char*)Qs + (it*8 + wave)*1024);
        }
        const int4 mv = *(const int4*)&amask[b*SS + q0 + wave*16 + quad*4];
        const int mr[4] = {mv.x, mv.y, mv.z, mv.w};
        // stage K tile kt=0 into buf 0
        #pragma unroll
        for (int it = 0; it < 2; ++it) {
            const int u = (it*8 + wave)*64 + lane;
            const int row = u >> 4, c = (u & 15) ^ (row & 7);
            if (c < 12)
                gload16(Kh + (size_t)row*QVW + c*8, (char*)Ks[0] + (it*8 + wave)*1024);
        }
        __syncthreads();
        // hoist Q fragments (loop-invariant across kt)
        short8 aq[3];
        #pragma unroll
        for (int ks = 0; ks < 3; ++ks)
            aq[ks] = *(short8*)&Qs[((wave*16 + n)*16 + ((ks*4 + quad) ^ sx))*8];

        int cur = 0;
        for (int kt = 0; kt <= ktmax; ++kt) {
            const int k0 = kt * 64;
            if (kt < ktmax) {   // prefetch next K tile
                #pragma unroll
                for (int it = 0; it < 2; ++it) {
                    const int u = (it*8 + wave)*64 + lane;
                    const int row = u >> 4, c = (u & 15) ^ (row & 7);
                    if (c < 12)
                        gload16(Kh + (size_t)(k0 + 64 + row)*QVW + c*8,
                                (char*)Ks[cur^1] + (it*8 + wave)*1024);
                }
            }
            // flush previous iteration's colsum (wave 0 only)
            if (kt > 0 && tid < 64) {
                const float s = colsum[cur^1][0][tid] + colsum[cur^1][1][tid]
                              + colsum[cur^1][2][tid] + colsum[cur^1][3][tid]
                              + colsum[cur^1][4][tid] + colsum[cur^1][5][tid]
                              + colsum[cur^1][6][tid] + colsum[cur^1][7][tid];
                lpq[(size_t)qt2*SS + (k0 - 64) + tid] = s;
            }
            #pragma unroll
            for (int ns = 0; ns < 4; ++ns) {
                f32x4 sa = (f32x4){0.f, 0.f, 0.f, 0.f};
                __builtin_amdgcn_s_setprio(1);
                #pragma unroll
                for (int ks = 0; ks < 3; ++ks) {
                    const short8 bk = *(short8*)&Ks[cur][((ns*16 + n)*16 + ((ks*4 + quad) ^ sx))*8];
                    sa = __builtin_amdgcn_mfma_f32_16x16x32_bf16(aq[ks], bk, sa, 0, 0, 0);
                }
                __builtin_amdgcn_s_setprio(0);
                const int kl = ns*16 + n;
                const int keyg = k0 + kl;
                float s = 0.f;
                #pragma unroll
                for (int r = 0; r < 4; ++r) {
                    const int qg = q0 + wave*16 + quad*4 + r;
                    const bool dead = (mr[r] != 0) || (keyg > qg);
                    s += dead ? 0.f : __expf(sa[r] * SM_SCALE);
                }
                s += __shfl_xor(s, 16);
                s += __shfl_xor(s, 32);
                if (quad == 0) colsum[cur][wave][kl] = s;
            }
            __syncthreads();
            cur ^= 1;
        }
        // final flush: last iter wrote colsum[ktmax&1] (= 1, ktmax odd)
        if (tid < 64) {
            const int pb = ktmax & 1;
            const float s = colsum[pb][0][tid] + colsum[pb][1][tid]
                          + colsum[pb][2][tid] + colsum[pb][3][tid]
                          + colsum[pb][4][tid] + colsum[pb][5][tid]
                          + colsum[pb][6][tid] + colsum[pb][7][tid];
            lpq[(size_t)qt2*SS + ktmax*64 + tid] = s;
        }
    }
}

// ---------------------------------------------------------------------------
// V' transpose+scale: QV's KV half -> (B,H,DK,S) bf16 scaled by 1/l_k, where
// l_k = sum over qt2 (128-row tiles) >= k0>>7 of lpart. grid (S/64, H, B).
// ---------------------------------------------------------------------------
__global__ __launch_bounds__(256) void transpose_scale(
    const ushort_t* __restrict__ QV, const float* __restrict__ lpart,
    ushort_t* __restrict__ Vt)
{
    __shared__ ushort_t T[64][104];
    __shared__ float rlv[64];
    const int tid = threadIdx.x;
    const int k0 = blockIdx.x * 64, h = blockIdx.y, b = blockIdx.z;
    const ushort_t* src = QV + (size_t)b*SS*QVW + DD + h*DKK;
    for (int s = tid; s < 768; s += 256) {
        const int r = s / 12, c = s % 12;
        *(short8*)&T[r][c*8] = *(const short8*)(src + (size_t)(k0 + r)*QVW + c*8);
    }
    if (tid < 64) {
        const float* lp = lpart + (size_t)(b*HH + h)*NT2*SS;
        float l = 0.f;
        for (int qt2 = k0 >> 7; qt2 < NT2; ++qt2) l += lp[(size_t)qt2*SS + k0 + tid];
        rlv[tid] = (l > 0.f) ? (1.f / l) : 0.f;
    }
    __syncthreads();
    ushort_t* dst = Vt + ((size_t)b*HH + h)*DKK*SS;
    for (int s = tid; s < 768; s += 256) {
        const int dk = s >> 3, c = s & 7;
        short8 v;
        #pragma unroll
        for (int i = 0; i < 8; ++i)
            v[i] = (short)f2b(b2f(T[c*8 + i][dk]) * rlv[c*8 + i]);
        *(short8*)(dst + (size_t)dk*SS + k0 + c*8) = v;
    }
}

// ---------------------------------------------------------------------------
// Pass 2: fused recompute + PV, 32x32 MFMA with swapped QK^T. 512 threads:
// waves 0-3 process qt2=px (light half), waves 4-7 process qt2=7-px (heavy
// half) CONCURRENTLY — 8 waves/CU (2/SIMD) instead of sequential halves at
// 1 wave/SIMD. Per-group private K/V double buffers (112 KB LDS). Inner
// per-iter structure identical to the R12-proven schedule: prefetch at iter
// top, QK -> exp -> cvt_pk/permlane pack -> PV, one barrier per iter. Loop
// count = heavy group's (block-uniform); light group guards out but keeps
// hitting barriers. XCD-grouped 1D grid (256 blocks).
// ---------------------------------------------------------------------------
__global__ __launch_bounds__(512, 1) void attn_pv_re(
    const ushort_t* __restrict__ QV, const int* __restrict__ amask,
    const ushort_t* __restrict__ Vt, ushort_t* __restrict__ O)
{
    __shared__ ushort_t Ks[2][2][64*128]; // [group][buf], 64 KB
    __shared__ ushort_t Vs[2][2][96*64];  // [group][buf], 48 KB
    const int tid = threadIdx.x, lane = tid & 63, wave = tid >> 6;
    const int grp = wave >> 2, w4 = wave & 3;
    const int ln31 = lane & 31, hi = lane >> 5;
    const int hwid = blockIdx.x;
    const int v = (hwid & 7) * 32 + (hwid >> 3);   // XCD-group same (b,h)
    const int px = v & 3, h = (v >> 2) & 7, b = v >> 5;
    const ushort_t* Qh = QV + (size_t)b*SS*QVW + h*DKK;
    const ushort_t* Kh = QV + (size_t)b*SS*QVW + DD + h*DKK;
    const ushort_t* Vth = Vt + ((size_t)b*HH + h)*DKK*SS;

    const int qt2 = grp ? (7 - px) : px;           // px in 0..3 -> grp1 heavy
    const int q0 = qt2 * 128;
    const int ktmax = 2*qt2 + 1;
    const int ktend = 2*(7 - px) + 1;              // = heavy group's ktmax
    const int qrow = q0 + w4*32 + ln31;
    // Q B-fragments (loop-invariant): Q[qrow][dk = t*16 + hi*8 .. +8]
    short8 bq[6];
    #pragma unroll
    for (int t = 0; t < 6; ++t)
        bq[t] = *(const short8*)(Qh + (size_t)qrow*QVW + t*16 + hi*8);
    const bool padq = amask[b*SS + qrow] != 0;

    // stage kt=0 into this group's buf 0 (both groups need kt=0)
    #pragma unroll
    for (int it = 0; it < 4; ++it) {
        const int u = (it*4 + w4)*64 + lane;       // 0..1023
        const int row = u >> 4, c = (u & 15) ^ (row & 7);
        if (c < 12)
            gload16(Kh + (size_t)row*QVW + c*8, (char*)Ks[grp][0] + (it*4 + w4)*1024);
    }
    #pragma unroll
    for (int it = 0; it < 3; ++it) {
        const int u = (it*4 + w4)*64 + lane;       // 0..767
        const int row = u >> 3, c = (u & 7) ^ (row & 7);
        gload16(Vth + (size_t)row*SS + c*8, (char*)Vs[grp][0] + (it*4 + w4)*1024);
    }
    __syncthreads();

    f32x16 acc[3];
    #pragma unroll
    for (int db = 0; db < 3; ++db)
        #pragma unroll
        for (int i = 0; i < 16; ++i) acc[db][i] = 0.f;

    int cur = 0;
    for (int kt = 0; kt <= ktend; ++kt) {
        const int k0 = kt * 64;
        if (kt < ktmax) {   // prefetch this group's next K/V tiles
            #pragma unroll
            for (int it = 0; it < 4; ++it) {
                const int u = (it*4 + w4)*64 + lane;
                const int row = u >> 4, c = (u & 15) ^ (row & 7);
                if (c < 12)
                    gload16(Kh + (size_t)(k0 + 64 + row)*QVW + c*8,
                            (char*)Ks[grp][cur^1] + (it*4 + w4)*1024);
            }
            #pragma unroll
            for (int it = 0; it < 3; ++it) {
                const int u = (it*4 + w4)*64 + lane;
                const int row = u >> 3, c = (u & 7) ^ (row & 7);
                gload16(Vth + (size_t)row*SS + k0 + 64 + c*8,
                        (char*)Vs[grp][cur^1] + (it*4 + w4)*1024);
            }
        }
        if (kt <= ktmax) {
            #pragma unroll
            for (int kb = 0; kb < 2; ++kb) {
                // swapped QK^T: D[k][q], q = ln31
                f32x16 sk;
                #pragma unroll
                for (int i = 0; i < 16; ++i) sk[i] = 0.f;
                const int krow = kb*32 + ln31;
                __builtin_amdgcn_s_setprio(1);
                #pragma unroll
                for (int t = 0; t < 6; ++t) {
                    const short8 ak = *(short8*)&Ks[grp][cur][krow*128 + (((t*2 + hi) ^ (krow & 7))*8)];
                    sk = __builtin_amdgcn_mfma_f32_32x32x16_bf16(ak, bq[t], sk, 0, 0, 0);
                }
                __builtin_amdgcn_s_setprio(0);
                // mask + exp (register-local: lane owns q-row qrow)
                const int kbase = k0 + kb*32 + 4*hi;
                float p[16];
                #pragma unroll
                for (int r = 0; r < 16; ++r) {
                    const int kg = kbase + (r & 3) + 8*(r >> 2);
                    const bool dead = padq || (kg > qrow);
                    p[r] = dead ? 0.f : __expf(sk[r] * SM_SCALE);
                }
                // pack f32->bf16 pairs, then swap halves across lane<32/>=32
                unsigned w[8];
                #pragma unroll
                for (int i = 0; i < 8; ++i)
                    asm("v_cvt_pk_bf16_f32 %0, %1, %2" : "=v"(w[i]) : "v"(p[2*i]), "v"(p[2*i+1]));
                plswap(w[0], w[2]);
                plswap(w[1], w[3]);
                plswap(w[4], w[6]);
                plswap(w[5], w[7]);
                // PV: acc[q][d] += E[q][k] * V'[dk][k]
                __builtin_amdgcn_s_setprio(1);
                #pragma unroll
                for (int s = 0; s < 2; ++s) {
                    short8 ae;
                    unsigned* aeu = (unsigned*)&ae;
                    aeu[0] = w[s*4 + 0]; aeu[1] = w[s*4 + 1];
                    aeu[2] = w[s*4 + 2]; aeu[3] = w[s*4 + 3];
                    #pragma unroll
                    for (int db = 0; db < 3; ++db) {
                        const int drow = db*32 + ln31;
                        const short8 bv = *(short8*)&Vs[grp][cur][drow*64 + (((kb*4 + s*2 + hi) ^ (drow & 7))*8)];
                        acc[db] = __builtin_amdgcn_mfma_f32_32x32x16_bf16(ae, bv, acc[db], 0, 0, 0);
                    }
                }
                __builtin_amdgcn_s_setprio(0);
            }
        }
        __syncthreads();
        cur ^= 1;
    }
    // epilogue: C/D row = (r&3)+8*(r>>2)+4*hi, col = ln31 (= d local)
    #pragma unroll
    for (int db = 0; db < 3; ++db) {
        #pragma unroll
        for (int r = 0; r < 16; ++r) {
            const int q = q0 + w4*32 + (r & 3) + 8*(r >> 2) + 4*hi;
            O[((size_t)b*SS + q)*DD + h*DKK + db*32 + ln31] = f2b(acc[db][r]);
        }
    }
}

// ---------------------------------------------------------------------------
// Residual + LayerNorm. X, R dtype per template; writes bf16 (or fp32 final).
// ---------------------------------------------------------------------------
__device__ __forceinline__ float block_sum256(float s, float* tmp4)
{
    #pragma unroll
    for (int off = 32; off > 0; off >>= 1) s += __shfl_down(s, off);
    __syncthreads();
    if ((threadIdx.x & 63) == 0) tmp4[threadIdx.x >> 6] = s;
    __syncthreads();
    return tmp4[0] + tmp4[1] + tmp4[2] + tmp4[3];
}

template<int XBF, int RBF, int OUTF32>
__global__ __launch_bounds__(256) void resid_ln(
    const void* __restrict__ X, const void* __restrict__ R,
    const float* __restrict__ g, const float* __restrict__ beta,
    ushort_t* __restrict__ OutB, float* __restrict__ OutF)
{
    __shared__ float tmp4[4];
    const int row = blockIdx.x;
    const int tid = threadIdx.x;
    float v[3], s = 0.f;
    #pragma unroll
    for (int i = 0; i < 3; ++i) {
        const size_t idx = (size_t)row * DD + tid + 256*i;
        const float xv = XBF ? b2f(((const ushort_t*)X)[idx]) : ((const float*)X)[idx];
        const float rv = RBF ? b2f(((const ushort_t*)R)[idx]) : ((const float*)R)[idx];
        v[i] = xv + rv;
        s += v[i];
    }
    const float mu = block_sum256(s, tmp4) * (1.f / DD);
    float qv = 0.f;
    #pragma unroll
    for (int i = 0; i < 3; ++i) { const float d = v[i] - mu; qv += d * d; }
    const float inv = rsqrtf(block_sum256(qv, tmp4) * (1.f / DD) + 1e-5f);
    #pragma unroll
    for (int i = 0; i < 3; ++i) {
        const int c = tid + 256*i;
        const float o = (v[i] - mu) * inv * g[c] + beta[c];
        if (OUTF32) OutF[(size_t)row * DD + c] = o;
        else        OutB[(size_t)row * DD + c] = f2b(o);
    }
}

// ---------------------------------------------------------------------------
extern "C" void kernel_launch(void* const* d_in, const int* in_sizes, int n_in,
                              void* d_out, int out_size, void* d_ws, size_t ws_size,
                              hipStream_t stream)
{
    (void)in_sizes; (void)n_in; (void)out_size; (void)ws_size;
    const float* x0    = (const float*)d_in[0];
    const int*   amask = (const int*)d_in[1];
    const float* a1_Wq = (const float*)d_in[2];
    const float* a1_bq = (const float*)d_in[3];
    const float* a1_Wv = (const float*)d_in[4];
    const float* a1_bv = (const float*)d_in[5];
    const float* a1_g  = (const float*)d_in[6];
    const float* a1_b  = (const float*)d_in[7];
    const float* a2_Wq = (const float*)d_in[8];
    const float* a2_bq = (const float*)d_in[9];
    const float* a2_Wv = (const float*)d_in[10];
    const float* a2_bv = (const float*)d_in[11];
    const float* a2_g  = (const float*)d_in[12];
    const float* a2_b  = (const float*)d_in[13];
    const float* f_W1  = (const float*)d_in[14];
    const float* f_b1  = (const float*)d_in[15];
    const float* f_W2  = (const float*)d_in[16];
    const float* f_b2  = (const float*)d_in[17];
    const float* f_g   = (const float*)d_in[18];
    const float* f_b   = (const float*)d_in[19];

    char* ws = (char*)d_ws;
    size_t off = 0;
    auto alloc = [&](size_t bytes) { void* p = ws + off; off += (bytes + 255) & ~(size_t)255; return p; };
    ushort_t* WqvT1 = (ushort_t*)alloc((size_t)QVW*DD*2);   // rows 0..767 Wq^T, 768..1535 Wv^T
    ushort_t* WqvT2 = (ushort_t*)alloc((size_t)QVW*DD*2);
    ushort_t* W1T   = (ushort_t*)alloc((size_t)DD*FFF*2);
    ushort_t* W2T   = (ushort_t*)alloc((size_t)DD*FFF*2);
    ushort_t* xb0   = (ushort_t*)alloc((size_t)MM*DD*2);    // bf16(x0)
    ushort_t* xb1   = (ushort_t*)alloc((size_t)MM*DD*2);    // x1 (post-LN layer 1)
    ushort_t* xb2   = (ushort_t*)alloc((size_t)MM*DD*2);    // x2 (post-LN layer 2)
    ushort_t* Ob    = (ushort_t*)alloc((size_t)MM*DD*2);    // attention O / FFN y
    ushort_t* QVb   = (ushort_t*)alloc((size_t)MM*QVW*2);   // Q | KV merged; aliased as hb
    ushort_t* hb    = QVb;                                  // M x FF bf16
    ushort_t* Vtb   = (ushort_t*)alloc((size_t)MM*DD*2);    // (B,H,DK,S) scaled V^T
    float* lpart = (float*)alloc((size_t)BB*HH*NT2*SS*4);   // 2 MB partial column sums
    float* out = (float*)d_out;

    const dim3 blk(256);
    const dim3 blk512(512);
    const dim3 gat(256);               // XCD-swizzled 1D grid for both attn passes
    const dim3 gtr(SS/64, HH, BB);

    prep_all<<<dim3(9984), blk, 0, stream>>>(
        a1_Wq, a1_Wv, a2_Wq, a2_Wv,
        WqvT1, WqvT1 + (size_t)DD*DD, WqvT2, WqvT2 + (size_t)DD*DD,
        f_W1, W1T, f_W2, W2T, x0, xb0);

    // ---- layer 1 ----
    gemm_bt<0><<<dim3((QVW/128)*(MM/128)), blk, 0, stream>>>(xb0, WqvT1, a1_bq, a1_bv, DD, QVb, DD, QVW);
    attn_sums<<<gat, blk512, 0, stream>>>(QVb, amask, lpart);
    transpose_scale<<<gtr, blk, 0, stream>>>(QVb, lpart, Vtb);
    attn_pv_re<<<gat, blk512, 0, stream>>>(QVb, amask, Vtb, Ob);
    resid_ln<1,0,0><<<dim3(MM), blk, 0, stream>>>(Ob, x0, a1_g, a1_b, xb1, nullptr);

    // ---- layer 2 ----
    gemm_bt<0><<<dim3((QVW/128)*(MM/128)), blk, 0, stream>>>(xb1, WqvT2, a2_bq, a2_bv, DD, QVb, DD, QVW);
    attn_sums<<<gat, blk512, 0, stream>>>(QVb, amask, lpart);
    transpose_scale<<<gtr, blk, 0, stream>>>(QVb, lpart, Vtb);
    attn_pv_re<<<gat, blk512, 0, stream>>>(QVb, amask, Vtb, Ob);
    resid_ln<1,1,0><<<dim3(MM), blk, 0, stream>>>(Ob, xb1, a2_g, a2_b, xb2, nullptr);

    // ---- FFN ----
    gemm_bt<1><<<dim3((FFF/128)*(MM/128)), blk, 0, stream>>>(xb2, W1T, f_b1, f_b1, FFF, hb, DD, FFF);
    gemm_bt<0><<<dim3((DD/128)*(MM/128)), blk, 0, stream>>>(hb, W2T, f_b2, f_b2, DD, Ob, FFF, DD);
    resid_ln<1,1,1><<<dim3(MM), blk, 0, stream>>>(Ob, xb2, f_g, f_b, nullptr, out);
}